// Round 5
// baseline (58815.826 us; speedup 1.0000x reference)
//
#include <hip/hip_runtime.h>
#include <stdint.h>
#include <math.h>

#define NB 1024      // batch
#define NH 256       // hidden
#define NG 1024      // 4*NH gate rows
#define NLOOK 336    // encoder steps
#define NHOR 168     // decoder steps
#define TPB 256
#define PLANE (NG * NH)   // 262144 elems per bf16 plane

// ---------- bf16 helpers (RNE) ----------
__device__ __forceinline__ unsigned short bf16_rne(float f) {
  union { float f; uint32_t u; } v; v.f = f;
  uint32_t u = v.u;
  u += 0x7FFFu + ((u >> 16) & 1u);
  return (unsigned short)(u >> 16);
}
__device__ __forceinline__ float bf16_f(unsigned short h) {
  union { uint32_t u; float f; } v; v.u = ((uint32_t)h) << 16;
  return v.f;
}
__device__ __forceinline__ float sigm(float x) { return 1.0f / (1.0f + expf(-x)); }

typedef short bf16x8 __attribute__((ext_vector_type(8)));
typedef float f32x4 __attribute__((ext_vector_type(4)));

// ---------- weight split prologue: W(fp32) -> hi/lo bf16 planes ----------
__global__ __launch_bounds__(TPB) void split_w(const float* __restrict__ W,
                                               unsigned short* __restrict__ hi,
                                               unsigned short* __restrict__ lo) {
  const int idx = blockIdx.x * TPB + threadIdx.x;
  const float w = W[idx];
  const unsigned short h = bf16_rne(w);
  hi[idx] = h;
  lo[idx] = bf16_rne(w - bf16_f(h));
}

// ---------- split-bf16 MFMA GEMM (proven in round 4) ----------
// Block tile: 64 batch rows x 64 gate cols (4 gates x 16 hcols at h0off).
// wave wv = m-tile (16 rows); lane: lg=l>>4 (k-group), ln16=l&15.
// A-frag: h[b0+wv*16+ln16][kt*32+lg*8 .. +7]; B-frag: W[g*256+h0off+ln16][same k].
// D: lane reg r -> row b0+wv*16+lg*4+r, col h0off+ln16.
__device__ __forceinline__ void gemm_acc(f32x4 acc[4],
                                         const unsigned short* __restrict__ hhi,
                                         const unsigned short* __restrict__ hlo,
                                         const unsigned short* __restrict__ whi,
                                         const unsigned short* __restrict__ wlo,
                                         int b0, int h0off, int wv, int lg, int ln16) {
  const int arow = b0 + wv * 16 + ln16;
  const unsigned short* ah = hhi + arow * NH;
  const unsigned short* al = hlo + arow * NH;
  const unsigned short* bh0 = whi + (h0off + ln16) * NH;
  const unsigned short* bl0 = wlo + (h0off + ln16) * NH;
#pragma unroll
  for (int kt = 0; kt < 8; ++kt) {
    const int ko = kt * 32 + lg * 8;
    const bf16x8 Ah = *(const bf16x8*)(ah + ko);
    const bf16x8 Al = *(const bf16x8*)(al + ko);
#pragma unroll
    for (int g = 0; g < 4; ++g) {
      const bf16x8 Bh = *(const bf16x8*)(bh0 + g * (NH * NH) + ko);
      const bf16x8 Bl = *(const bf16x8*)(bl0 + g * (NH * NH) + ko);
      acc[g] = __builtin_amdgcn_mfma_f32_16x16x32_bf16(Ah, Bh, acc[g], 0, 0, 0);
      acc[g] = __builtin_amdgcn_mfma_f32_16x16x32_bf16(Ah, Bl, acc[g], 0, 0, 0);
      acc[g] = __builtin_amdgcn_mfma_f32_16x16x32_bf16(Al, Bh, acc[g], 0, 0, 0);
    }
  }
}

// ---------- 16-block btile-group barrier ----------
// Each block owns one 64B-padded monotonic flag; arrive = release-store step,
// wait = 16-lane vector poll until all flags >= step. Agent-scope fences make
// normal stores/loads of h-planes visible across XCDs.
__device__ __forceinline__ void barrier16(unsigned* flags, int bt, int ht, unsigned target) {
  __threadfence();
  __syncthreads();
  if (threadIdx.x < 64) {
    const int l = threadIdx.x;
    if (l == 0)
      __hip_atomic_store(&flags[(bt * 16 + ht) * 16], target,
                         __ATOMIC_RELEASE, __HIP_MEMORY_SCOPE_AGENT);
    for (;;) {
      unsigned v = (l < 16)
          ? __hip_atomic_load(&flags[(bt * 16 + l) * 16],
                              __ATOMIC_ACQUIRE, __HIP_MEMORY_SCOPE_AGENT)
          : target;
      if (__all(v >= target)) break;
      __builtin_amdgcn_s_sleep(2);
    }
  }
  __syncthreads();
  __threadfence();
}

// ---------- the whole network in one launch ----------
__global__ __launch_bounds__(TPB, 1) void lstm_persist(
    const float* __restrict__ x,
    const float* __restrict__ eWih0, const float* __restrict__ eb0,
    const float* __restrict__ eb1,
    const float* __restrict__ dWih0, const float* __restrict__ db0,
    const float* __restrict__ db1,
    const float* __restrict__ fcW, const float* __restrict__ fcb,
    const unsigned short* __restrict__ wp,   // 12 planes: {hi,lo} x {eWhh0,eWih1,eWhh1,dWhh0,dWih1,dWhh1}
    unsigned short* __restrict__ hbase,      // 8 h planes
    unsigned* __restrict__ flags,
    float* __restrict__ pred,                // [NHOR][NB]
    float* __restrict__ out) {
  const int tx = threadIdx.x, bx = blockIdx.x;
  const int bt = bx & 15, ht = bx >> 4;   // bt in low bits: group likely XCD-local (perf only)
  const int b0 = bt * 64, h0off = ht * 16;
  const int wv = tx >> 6, l = tx & 63, lg = l >> 4, ln16 = l & 15;
  const int hcol = h0off + ln16;

  const unsigned short* W_eWhh0_hi = wp + 0 * 2 * PLANE;
  const unsigned short* W_eWhh0_lo = W_eWhh0_hi + PLANE;
  const unsigned short* W_eWih1_hi = wp + 1 * 2 * PLANE;
  const unsigned short* W_eWih1_lo = W_eWih1_hi + PLANE;
  const unsigned short* W_eWhh1_hi = wp + 2 * 2 * PLANE;
  const unsigned short* W_eWhh1_lo = W_eWhh1_hi + PLANE;
  const unsigned short* W_dWhh0_hi = wp + 3 * 2 * PLANE;
  const unsigned short* W_dWhh0_lo = W_dWhh0_hi + PLANE;
  const unsigned short* W_dWih1_hi = wp + 4 * 2 * PLANE;
  const unsigned short* W_dWih1_lo = W_dWih1_hi + PLANE;
  const unsigned short* W_dWhh1_hi = wp + 5 * 2 * PLANE;
  const unsigned short* W_dWhh1_lo = W_dWhh1_hi + PLANE;

  unsigned short* h0c_hi = hbase + 0 * PLANE; unsigned short* h0c_lo = hbase + 1 * PLANE;
  unsigned short* h0n_hi = hbase + 2 * PLANE; unsigned short* h0n_lo = hbase + 3 * PLANE;
  unsigned short* h1c_hi = hbase + 4 * PLANE; unsigned short* h1c_lo = hbase + 5 * PLANE;
  unsigned short* h1n_hi = hbase + 6 * PLANE; unsigned short* h1n_lo = hbase + 7 * PLANE;

  // per-thread constants
  float ewv[4], eb0v[4], eb1v[4], dwv[4], db0v[4], db1v[4];
#pragma unroll
  for (int g = 0; g < 4; ++g) {
    ewv[g]  = eWih0[g * NH + hcol];
    eb0v[g] = eb0[g * NH + hcol];
    eb1v[g] = eb1[g * NH + hcol];
    dwv[g]  = dWih0[g * NH + hcol];
    db0v[g] = db0[g * NH + hcol];
    db1v[g] = db1[g * NH + hcol];
  }
  const float fcwv = fcW[hcol];
  const float fcbv = fcb[0];

  float c0r[4] = {0.f, 0.f, 0.f, 0.f};
  float c1r[4] = {0.f, 0.f, 0.f, 0.f};
  unsigned step = 0;

  // ---------------- encoder ----------------
  for (int t = 0; t < NLOOK; ++t) {
    f32x4 acc[4] = {};
    if (t > 0) gemm_acc(acc, h0c_hi, h0c_lo, W_eWhh0_hi, W_eWhh0_lo, b0, h0off, wv, lg, ln16);
#pragma unroll
    for (int r = 0; r < 4; ++r) {
      const int b = b0 + wv * 16 + lg * 4 + r;
      const float pv = x[b * NLOOK + t];
      const float ig = sigm(acc[0][r] + pv * ewv[0] + eb0v[0]);
      const float fg = sigm(acc[1][r] + pv * ewv[1] + eb0v[1]);
      const float gg = tanhf(acc[2][r] + pv * ewv[2] + eb0v[2]);
      const float og = sigm(acc[3][r] + pv * ewv[3] + eb0v[3]);
      c0r[r] = fg * c0r[r] + ig * gg;
      const float hv = og * tanhf(c0r[r]);
      const unsigned short hb = bf16_rne(hv);
      h0n_hi[b * NH + hcol] = hb;
      h0n_lo[b * NH + hcol] = bf16_rne(hv - bf16_f(hb));
    }
    ++step; barrier16(flags, bt, ht, step);

    f32x4 a2[4] = {};
    gemm_acc(a2, h0n_hi, h0n_lo, W_eWih1_hi, W_eWih1_lo, b0, h0off, wv, lg, ln16);
    if (t > 0) gemm_acc(a2, h1c_hi, h1c_lo, W_eWhh1_hi, W_eWhh1_lo, b0, h0off, wv, lg, ln16);
#pragma unroll
    for (int r = 0; r < 4; ++r) {
      const int b = b0 + wv * 16 + lg * 4 + r;
      const float ig = sigm(a2[0][r] + eb1v[0]);
      const float fg = sigm(a2[1][r] + eb1v[1]);
      const float gg = tanhf(a2[2][r] + eb1v[2]);
      const float og = sigm(a2[3][r] + eb1v[3]);
      c1r[r] = fg * c1r[r] + ig * gg;
      const float hv = og * tanhf(c1r[r]);
      const unsigned short hb = bf16_rne(hv);
      h1n_hi[b * NH + hcol] = hb;
      h1n_lo[b * NH + hcol] = bf16_rne(hv - bf16_f(hb));
    }
    ++step; barrier16(flags, bt, ht, step);

    { unsigned short* s0 = h0c_hi; h0c_hi = h0n_hi; h0n_hi = s0; }
    { unsigned short* s0 = h0c_lo; h0c_lo = h0n_lo; h0n_lo = s0; }
    { unsigned short* s0 = h1c_hi; h1c_hi = h1n_hi; h1n_hi = s0; }
    { unsigned short* s0 = h1c_lo; h1c_lo = h1n_lo; h1n_lo = s0; }
  }

  // ---------------- decoder (autoregressive) ----------------
  for (int t = 0; t < NHOR; ++t) {
    f32x4 acc[4] = {};
    gemm_acc(acc, h0c_hi, h0c_lo, W_dWhh0_hi, W_dWhh0_lo, b0, h0off, wv, lg, ln16);
#pragma unroll
    for (int r = 0; r < 4; ++r) {
      const int b = b0 + wv * 16 + lg * 4 + r;
      const float pv = (t == 0) ? x[b * NLOOK + (NLOOK - 1)] : pred[(t - 1) * NB + b];
      const float ig = sigm(acc[0][r] + pv * dwv[0] + db0v[0]);
      const float fg = sigm(acc[1][r] + pv * dwv[1] + db0v[1]);
      const float gg = tanhf(acc[2][r] + pv * dwv[2] + db0v[2]);
      const float og = sigm(acc[3][r] + pv * dwv[3] + db0v[3]);
      c0r[r] = fg * c0r[r] + ig * gg;
      const float hv = og * tanhf(c0r[r]);
      const unsigned short hb = bf16_rne(hv);
      h0n_hi[b * NH + hcol] = hb;
      h0n_lo[b * NH + hcol] = bf16_rne(hv - bf16_f(hb));
    }
    ++step; barrier16(flags, bt, ht, step);

    f32x4 a2[4] = {};
    gemm_acc(a2, h0n_hi, h0n_lo, W_dWih1_hi, W_dWih1_lo, b0, h0off, wv, lg, ln16);
    gemm_acc(a2, h1c_hi, h1c_lo, W_dWhh1_hi, W_dWhh1_lo, b0, h0off, wv, lg, ln16);
    float hvr[4];
#pragma unroll
    for (int r = 0; r < 4; ++r) {
      const int b = b0 + wv * 16 + lg * 4 + r;
      const float ig = sigm(a2[0][r] + db1v[0]);
      const float fg = sigm(a2[1][r] + db1v[1]);
      const float gg = tanhf(a2[2][r] + db1v[2]);
      const float og = sigm(a2[3][r] + db1v[3]);
      c1r[r] = fg * c1r[r] + ig * gg;
      hvr[r] = og * tanhf(c1r[r]);
      const unsigned short hb = bf16_rne(hvr[r]);
      h1n_hi[b * NH + hcol] = hb;
      h1n_lo[b * NH + hcol] = bf16_rne(hvr[r] - bf16_f(hb));
    }
    // fc: reduce 16 h-cols per lg-group, one atomic per row
    float s[4];
#pragma unroll
    for (int r = 0; r < 4; ++r) s[r] = hvr[r] * fcwv;
#pragma unroll
    for (int m = 1; m < 16; m <<= 1) {
#pragma unroll
      for (int r = 0; r < 4; ++r) s[r] += __shfl_xor(s[r], m, 64);
    }
    if (ln16 == 0) {
#pragma unroll
      for (int r = 0; r < 4; ++r) {
        const int b = b0 + wv * 16 + lg * 4 + r;
        float v = s[r];
        if (ht == 0) v += fcbv;
        atomicAdd(&pred[t * NB + b], v);
      }
    }
    ++step; barrier16(flags, bt, ht, step);

    { unsigned short* s0 = h0c_hi; h0c_hi = h0n_hi; h0n_hi = s0; }
    { unsigned short* s0 = h0c_lo; h0c_lo = h0n_lo; h0n_lo = s0; }
    { unsigned short* s0 = h1c_hi; h1c_hi = h1n_hi; h1n_hi = s0; }
    { unsigned short* s0 = h1c_lo; h1c_lo = h1n_lo; h1n_lo = s0; }
  }

  // ---------------- output epilogue ----------------
  if (ht == 0 && tx < 64) {
    const int b = b0 + tx;
    for (int t = 0; t < NHOR; ++t) out[b * NHOR + t] = pred[t * NB + b];
  }
}

extern "C" void kernel_launch(void* const* d_in, const int* in_sizes, int n_in,
                              void* d_out, int out_size, void* d_ws, size_t ws_size,
                              hipStream_t stream) {
  (void)in_sizes; (void)n_in; (void)out_size; (void)ws_size;
  const float* x     = (const float*)d_in[0];
  const float* eWih0 = (const float*)d_in[1];
  const float* eWhh0 = (const float*)d_in[2];
  const float* eb0   = (const float*)d_in[3];
  const float* eWih1 = (const float*)d_in[4];
  const float* eWhh1 = (const float*)d_in[5];
  const float* eb1   = (const float*)d_in[6];
  const float* dWih0 = (const float*)d_in[7];
  const float* dWhh0 = (const float*)d_in[8];
  const float* db0   = (const float*)d_in[9];
  const float* dWih1 = (const float*)d_in[10];
  const float* dWhh1 = (const float*)d_in[11];
  const float* db1   = (const float*)d_in[12];
  const float* fcW   = (const float*)d_in[13];
  const float* fcb   = (const float*)d_in[14];
  float* out = (float*)d_out;

  uint8_t* wsb = (uint8_t*)d_ws;
  unsigned* flags = (unsigned*)wsb;                          // 16*16*64B = 16 KiB
  float* pred = (float*)(wsb + 16384);                       // NHOR*NB*4 = 688128 B
  unsigned short* wp = (unsigned short*)(wsb + 1048576);     // 12 planes = 6 MiB
  unsigned short* hbase = (unsigned short*)(wsb + 1048576 + (size_t)12 * PLANE * 2);  // 8 planes = 4 MiB

  // zero flags + pred (poisoned 0xAA by harness; graph-capturable async memset)
  hipMemsetAsync(d_ws, 0, 16384 + (size_t)NHOR * NB * 4, stream);

  // split weights into hi/lo bf16 planes
  const float* Wsrc[6] = { eWhh0, eWih1, eWhh1, dWhh0, dWih1, dWhh1 };
  for (int m = 0; m < 6; ++m)
    split_w<<<dim3(PLANE / TPB), dim3(TPB), 0, stream>>>(
        Wsrc[m], wp + (size_t)m * 2 * PLANE, wp + (size_t)m * 2 * PLANE + PLANE);

  lstm_persist<<<dim3(256), dim3(TPB), 0, stream>>>(
      x, eWih0, eb0, eb1, dWih0, db0, db1, fcW, fcb,
      wp, hbase, flags, pred, out);
}

// Round 6
// 21466.757 us; speedup vs baseline: 2.7399x; 2.7399x over previous
//
#include <hip/hip_runtime.h>
#include <stdint.h>
#include <math.h>

#define NB 1024      // batch
#define NH 256       // hidden
#define NG 1024      // 4*NH gate rows
#define NLOOK 336    // encoder steps
#define NHOR 168     // decoder steps
#define TPB 256
#define PLANE (NG * NH)   // 262144 elems per bf16 weight plane

// ---------- bf16 helpers (RNE) ----------
__device__ __forceinline__ unsigned short bf16_rne(float f) {
  union { float f; uint32_t u; } v; v.f = f;
  uint32_t u = v.u;
  u += 0x7FFFu + ((u >> 16) & 1u);
  return (unsigned short)(u >> 16);
}
__device__ __forceinline__ float bf16_f(unsigned short h) {
  union { uint32_t u; float f; } v; v.u = ((uint32_t)h) << 16;
  return v.f;
}
__device__ __forceinline__ float sigm(float x) { return 1.0f / (1.0f + expf(-x)); }
// pack h as (hi<<16)|lo where hi=bf16(h), lo=bf16(h - hi)
__device__ __forceinline__ uint32_t pack_h(float hv) {
  const unsigned short hb = bf16_rne(hv);
  const unsigned short lb = bf16_rne(hv - bf16_f(hb));
  return ((uint32_t)hb << 16) | (uint32_t)lb;
}

typedef short bf16x8 __attribute__((ext_vector_type(8)));
typedef float f32x4 __attribute__((ext_vector_type(4)));

// ---------- weight split prologue: W(fp32) -> hi/lo bf16 planes ----------
__global__ __launch_bounds__(TPB) void split_w(const float* __restrict__ W,
                                               unsigned short* __restrict__ hi,
                                               unsigned short* __restrict__ lo) {
  const int idx = blockIdx.x * TPB + threadIdx.x;
  const float w = W[idx];
  const unsigned short h = bf16_rne(w);
  hi[idx] = h;
  lo[idx] = bf16_rne(w - bf16_f(h));
}

// ---------- split-bf16 MFMA GEMM, A from packed-u32 plane via LLC atomics ----------
// Block tile: 64 batch rows x 64 gate cols (4 gates x 16 hcols at h0off).
// wave wv = m-tile; lane: lg=l>>4 (k-group), ln16=l&15.
// A-frag: hp[b0+wv*16+ln16][kt*32+lg*8 .. +7] (8 u32 = 4 atomic u64 loads, unpack hi/lo)
// B-frag: W[g*256+h0off+ln16][same k] (normal loads, L2-resident)
// D: lane reg r -> row b0+wv*16+lg*4+r, col h0off+ln16.
__device__ __forceinline__ void gemm_packed(f32x4 acc[4],
                                            const uint32_t* __restrict__ hp,
                                            const unsigned short* __restrict__ whi,
                                            const unsigned short* __restrict__ wlo,
                                            int b0, int h0off, int wv, int lg, int ln16) {
  const uint32_t* ap = hp + (size_t)(b0 + wv * 16 + ln16) * NH;
  const unsigned short* bh0 = whi + (size_t)(h0off + ln16) * NH;
  const unsigned short* bl0 = wlo + (size_t)(h0off + ln16) * NH;

  // hoist all A loads (LLC latency ~700cy, pipelined)
  unsigned long long araw[32];
#pragma unroll
  for (int kt = 0; kt < 8; ++kt) {
    const int ko = kt * 32 + lg * 8;
#pragma unroll
    for (int e = 0; e < 4; ++e)
      araw[kt * 4 + e] = __hip_atomic_load(
          (const unsigned long long*)(ap + ko) + e,
          __ATOMIC_RELAXED, __HIP_MEMORY_SCOPE_AGENT);
  }

#pragma unroll
  for (int kt = 0; kt < 8; ++kt) {
    uint32_t p[8];
#pragma unroll
    for (int e = 0; e < 4; ++e) {
      p[2 * e]     = (uint32_t)araw[kt * 4 + e];
      p[2 * e + 1] = (uint32_t)(araw[kt * 4 + e] >> 32);
    }
    bf16x8 Ah, Al;
#pragma unroll
    for (int e = 0; e < 8; ++e) {
      Ah[e] = (short)(p[e] >> 16);
      Al[e] = (short)(p[e] & 0xFFFFu);
    }
    const int ko = kt * 32 + lg * 8;
#pragma unroll
    for (int g = 0; g < 4; ++g) {
      const bf16x8 Bh = *(const bf16x8*)(bh0 + (size_t)g * (NH * NH) + ko);
      const bf16x8 Bl = *(const bf16x8*)(bl0 + (size_t)g * (NH * NH) + ko);
      acc[g] = __builtin_amdgcn_mfma_f32_16x16x32_bf16(Ah, Bh, acc[g], 0, 0, 0);
      acc[g] = __builtin_amdgcn_mfma_f32_16x16x32_bf16(Ah, Bl, acc[g], 0, 0, 0);
      acc[g] = __builtin_amdgcn_mfma_f32_16x16x32_bf16(Al, Bh, acc[g], 0, 0, 0);
    }
  }
}

// ---------- 16-block btile-group barrier, L2-neutral ----------
// __syncthreads drains this block's (atomic) stores; one release flag store;
// RELAXED polling (no per-iteration cache invalidation!).
__device__ __forceinline__ void group_barrier(unsigned* flags, int bt, int ht, unsigned target) {
  __syncthreads();
  const int tx = threadIdx.x;
  if (tx == 0)
    __hip_atomic_store(&flags[(bt * 16 + ht) * 16], target,
                       __ATOMIC_RELEASE, __HIP_MEMORY_SCOPE_AGENT);
  if (tx < 16) {
    while (__hip_atomic_load(&flags[(bt * 16 + tx) * 16],
                             __ATOMIC_RELAXED, __HIP_MEMORY_SCOPE_AGENT) < target)
      __builtin_amdgcn_s_sleep(1);
  }
  __syncthreads();
  asm volatile("" ::: "memory");
}

// ---------- the whole network in one launch ----------
__global__ __launch_bounds__(TPB, 1) void lstm_persist(
    const float* __restrict__ x,
    const float* __restrict__ eWih0, const float* __restrict__ eb0,
    const float* __restrict__ eb1,
    const float* __restrict__ dWih0, const float* __restrict__ db0,
    const float* __restrict__ db1,
    const float* __restrict__ fcW, const float* __restrict__ fcb,
    const unsigned short* __restrict__ wp,  // 12 planes: {hi,lo} x {eWhh0,eWih1,eWhh1,dWhh0,dWih1,dWhh1}
    uint32_t* __restrict__ hbase,           // 4 packed h planes (h0 a/b, h1 a/b)
    unsigned* __restrict__ flags,
    float* __restrict__ pred,               // [NHOR][NB]
    float* __restrict__ out) {
  const int tx = threadIdx.x, bx = blockIdx.x;
  const int bt = bx & 15, ht = bx >> 4;
  const int b0 = bt * 64, h0off = ht * 16;
  const int wv = tx >> 6, l = tx & 63, lg = l >> 4, ln16 = l & 15;
  const int hcol = h0off + ln16;

  const unsigned short* W_eWhh0_hi = wp + 0 * 2 * PLANE;
  const unsigned short* W_eWhh0_lo = W_eWhh0_hi + PLANE;
  const unsigned short* W_eWih1_hi = wp + 1 * 2 * PLANE;
  const unsigned short* W_eWih1_lo = W_eWih1_hi + PLANE;
  const unsigned short* W_eWhh1_hi = wp + 2 * 2 * PLANE;
  const unsigned short* W_eWhh1_lo = W_eWhh1_hi + PLANE;
  const unsigned short* W_dWhh0_hi = wp + 3 * 2 * PLANE;
  const unsigned short* W_dWhh0_lo = W_dWhh0_hi + PLANE;
  const unsigned short* W_dWih1_hi = wp + 4 * 2 * PLANE;
  const unsigned short* W_dWih1_lo = W_dWih1_hi + PLANE;
  const unsigned short* W_dWhh1_hi = wp + 5 * 2 * PLANE;
  const unsigned short* W_dWhh1_lo = W_dWhh1_hi + PLANE;

  const int HP = NB * NH;  // 262144 u32 per h plane
  uint32_t* h0c = hbase + 0 * HP; uint32_t* h0n = hbase + 1 * HP;
  uint32_t* h1c = hbase + 2 * HP; uint32_t* h1n = hbase + 3 * HP;

  // per-thread constants
  float ewv[4], eb0v[4], eb1v[4], dwv[4], db0v[4], db1v[4];
#pragma unroll
  for (int g = 0; g < 4; ++g) {
    ewv[g]  = eWih0[g * NH + hcol];
    eb0v[g] = eb0[g * NH + hcol];
    eb1v[g] = eb1[g * NH + hcol];
    dwv[g]  = dWih0[g * NH + hcol];
    db0v[g] = db0[g * NH + hcol];
    db1v[g] = db1[g * NH + hcol];
  }
  const float fcwv = fcW[hcol];
  const float fcbv = fcb[0];

  float c0r[4] = {0.f, 0.f, 0.f, 0.f};
  float c1r[4] = {0.f, 0.f, 0.f, 0.f};
  unsigned step = 0;

  // ---------------- encoder ----------------
  for (int t = 0; t < NLOOK; ++t) {
    f32x4 acc[4] = {};
    if (t > 0) gemm_packed(acc, h0c, W_eWhh0_hi, W_eWhh0_lo, b0, h0off, wv, lg, ln16);
#pragma unroll
    for (int r = 0; r < 4; ++r) {
      const int b = b0 + wv * 16 + lg * 4 + r;
      const float pv = x[b * NLOOK + t];
      const float ig = sigm(acc[0][r] + pv * ewv[0] + eb0v[0]);
      const float fg = sigm(acc[1][r] + pv * ewv[1] + eb0v[1]);
      const float gg = tanhf(acc[2][r] + pv * ewv[2] + eb0v[2]);
      const float og = sigm(acc[3][r] + pv * ewv[3] + eb0v[3]);
      c0r[r] = fg * c0r[r] + ig * gg;
      const float hv = og * tanhf(c0r[r]);
      __hip_atomic_store(&h0n[b * NH + hcol], pack_h(hv),
                         __ATOMIC_RELAXED, __HIP_MEMORY_SCOPE_AGENT);
    }
    ++step; group_barrier(flags, bt, ht, step);

    f32x4 a2[4] = {};
    gemm_packed(a2, h0n, W_eWih1_hi, W_eWih1_lo, b0, h0off, wv, lg, ln16);
    if (t > 0) gemm_packed(a2, h1c, W_eWhh1_hi, W_eWhh1_lo, b0, h0off, wv, lg, ln16);
#pragma unroll
    for (int r = 0; r < 4; ++r) {
      const int b = b0 + wv * 16 + lg * 4 + r;
      const float ig = sigm(a2[0][r] + eb1v[0]);
      const float fg = sigm(a2[1][r] + eb1v[1]);
      const float gg = tanhf(a2[2][r] + eb1v[2]);
      const float og = sigm(a2[3][r] + eb1v[3]);
      c1r[r] = fg * c1r[r] + ig * gg;
      const float hv = og * tanhf(c1r[r]);
      __hip_atomic_store(&h1n[b * NH + hcol], pack_h(hv),
                         __ATOMIC_RELAXED, __HIP_MEMORY_SCOPE_AGENT);
    }
    ++step; group_barrier(flags, bt, ht, step);

    { uint32_t* s0 = h0c; h0c = h0n; h0n = s0; }
    { uint32_t* s0 = h1c; h1c = h1n; h1n = s0; }
  }

  // ---------------- decoder (autoregressive) ----------------
  for (int t = 0; t < NHOR; ++t) {
    // fetch feedback input early (LLC latency hides under gemm)
    float pv[4];
#pragma unroll
    for (int r = 0; r < 4; ++r) {
      const int b = b0 + wv * 16 + lg * 4 + r;
      pv[r] = (t == 0)
          ? x[b * NLOOK + (NLOOK - 1)]
          : __hip_atomic_load(&pred[(t - 1) * NB + b],
                              __ATOMIC_RELAXED, __HIP_MEMORY_SCOPE_AGENT);
    }

    f32x4 acc[4] = {};
    gemm_packed(acc, h0c, W_dWhh0_hi, W_dWhh0_lo, b0, h0off, wv, lg, ln16);
#pragma unroll
    for (int r = 0; r < 4; ++r) {
      const int b = b0 + wv * 16 + lg * 4 + r;
      const float ig = sigm(acc[0][r] + pv[r] * dwv[0] + db0v[0]);
      const float fg = sigm(acc[1][r] + pv[r] * dwv[1] + db0v[1]);
      const float gg = tanhf(acc[2][r] + pv[r] * dwv[2] + db0v[2]);
      const float og = sigm(acc[3][r] + pv[r] * dwv[3] + db0v[3]);
      c0r[r] = fg * c0r[r] + ig * gg;
      const float hv = og * tanhf(c0r[r]);
      __hip_atomic_store(&h0n[b * NH + hcol], pack_h(hv),
                         __ATOMIC_RELAXED, __HIP_MEMORY_SCOPE_AGENT);
    }
    ++step; group_barrier(flags, bt, ht, step);

    f32x4 a2[4] = {};
    gemm_packed(a2, h0n, W_dWih1_hi, W_dWih1_lo, b0, h0off, wv, lg, ln16);
    gemm_packed(a2, h1c, W_dWhh1_hi, W_dWhh1_lo, b0, h0off, wv, lg, ln16);
    float hvr[4];
#pragma unroll
    for (int r = 0; r < 4; ++r) {
      const int b = b0 + wv * 16 + lg * 4 + r;
      const float ig = sigm(a2[0][r] + db1v[0]);
      const float fg = sigm(a2[1][r] + db1v[1]);
      const float gg = tanhf(a2[2][r] + db1v[2]);
      const float og = sigm(a2[3][r] + db1v[3]);
      c1r[r] = fg * c1r[r] + ig * gg;
      hvr[r] = og * tanhf(c1r[r]);
      __hip_atomic_store(&h1n[b * NH + hcol], pack_h(hvr[r]),
                         __ATOMIC_RELAXED, __HIP_MEMORY_SCOPE_AGENT);
    }
    // fc: reduce 16 h-cols per lg-group, one atomicAdd per batch row
    float s[4];
#pragma unroll
    for (int r = 0; r < 4; ++r) s[r] = hvr[r] * fcwv;
#pragma unroll
    for (int m = 1; m < 16; m <<= 1) {
#pragma unroll
      for (int r = 0; r < 4; ++r) s[r] += __shfl_xor(s[r], m, 64);
    }
    if (ln16 == 0) {
#pragma unroll
      for (int r = 0; r < 4; ++r) {
        const int b = b0 + wv * 16 + lg * 4 + r;
        float v = s[r];
        if (ht == 0) v += fcbv;
        atomicAdd(&pred[t * NB + b], v);
      }
    }
    ++step; group_barrier(flags, bt, ht, step);

    // publish this step's predictions (plain stores, flushed at kernel end)
    if (ht == 0 && tx < 64) {
      const int b = b0 + tx;
      const float pw = __hip_atomic_load(&pred[t * NB + b],
                                         __ATOMIC_RELAXED, __HIP_MEMORY_SCOPE_AGENT);
      out[b * NHOR + t] = pw;
    }

    { uint32_t* s0 = h0c; h0c = h0n; h0n = s0; }
    { uint32_t* s0 = h1c; h1c = h1n; h1n = s0; }
  }
}

extern "C" void kernel_launch(void* const* d_in, const int* in_sizes, int n_in,
                              void* d_out, int out_size, void* d_ws, size_t ws_size,
                              hipStream_t stream) {
  (void)in_sizes; (void)n_in; (void)out_size; (void)ws_size;
  const float* x     = (const float*)d_in[0];
  const float* eWih0 = (const float*)d_in[1];
  const float* eWhh0 = (const float*)d_in[2];
  const float* eb0   = (const float*)d_in[3];
  const float* eWih1 = (const float*)d_in[4];
  const float* eWhh1 = (const float*)d_in[5];
  const float* eb1   = (const float*)d_in[6];
  const float* dWih0 = (const float*)d_in[7];
  const float* dWhh0 = (const float*)d_in[8];
  const float* db0   = (const float*)d_in[9];
  const float* dWih1 = (const float*)d_in[10];
  const float* dWhh1 = (const float*)d_in[11];
  const float* db1   = (const float*)d_in[12];
  const float* fcW   = (const float*)d_in[13];
  const float* fcb   = (const float*)d_in[14];
  float* out = (float*)d_out;

  uint8_t* wsb = (uint8_t*)d_ws;
  unsigned* flags = (unsigned*)wsb;                            // 16*16*64B = 16 KiB
  float* pred = (float*)(wsb + 16384);                         // NHOR*NB*4 = 688128 B
  unsigned short* wp = (unsigned short*)(wsb + 1048576);       // 12 planes = 6 MiB
  uint32_t* hbase = (uint32_t*)(wsb + 1048576 + (size_t)12 * PLANE * 2);  // 4 packed planes = 4 MiB

  // zero flags + pred (graph-capturable async memset)
  hipMemsetAsync(d_ws, 0, 16384 + (size_t)NHOR * NB * 4, stream);

  // split weights into hi/lo bf16 planes
  const float* Wsrc[6] = { eWhh0, eWih1, eWhh1, dWhh0, dWih1, dWhh1 };
  for (int m = 0; m < 6; ++m)
    split_w<<<dim3(PLANE / TPB), dim3(TPB), 0, stream>>>(
        Wsrc[m], wp + (size_t)m * 2 * PLANE, wp + (size_t)m * 2 * PLANE + PLANE);

  lstm_persist<<<dim3(256), dim3(TPB), 0, stream>>>(
      x, eWih0, eb0, eb1, dWih0, db0, db1, fcW, fcb,
      wp, hbase, flags, pred, out);
}

// Round 7
// 16479.085 us; speedup vs baseline: 3.5691x; 1.3027x over previous
//
#include <hip/hip_runtime.h>
#include <stdint.h>
#include <math.h>

#define NB 1024      // batch
#define NH 256       // hidden
#define NG 1024      // 4*NH gate rows
#define NLOOK 336    // encoder steps
#define NHOR 168     // decoder steps
#define TPB 256
#define PLANE (NG * NH)   // 262144 elems per bf16 weight plane

// ---------- bf16 helpers (RNE) ----------
__device__ __forceinline__ unsigned short bf16_rne(float f) {
  union { float f; uint32_t u; } v; v.f = f;
  uint32_t u = v.u;
  u += 0x7FFFu + ((u >> 16) & 1u);
  return (unsigned short)(u >> 16);
}
__device__ __forceinline__ float bf16_f(unsigned short h) {
  union { uint32_t u; float f; } v; v.u = ((uint32_t)h) << 16;
  return v.f;
}
// fast sigmoid/tanh on hw trans pipes (~1e-7 rel err; bf16 split err dominates)
__device__ __forceinline__ float sigm(float x) {
  return __builtin_amdgcn_rcpf(1.0f + __expf(-x));
}
__device__ __forceinline__ float tanh_(float x) {
  return 1.0f - 2.0f * __builtin_amdgcn_rcpf(1.0f + __expf(2.0f * x));
}
// pack h as (hi<<16)|lo where hi=bf16(h), lo=bf16(h - hi)
__device__ __forceinline__ uint32_t pack_h(float hv) {
  const unsigned short hb = bf16_rne(hv);
  const unsigned short lb = bf16_rne(hv - bf16_f(hb));
  return ((uint32_t)hb << 16) | (uint32_t)lb;
}

typedef short bf16x8 __attribute__((ext_vector_type(8)));
typedef float f32x4 __attribute__((ext_vector_type(4)));

// ---------- weight split prologue: W(fp32) -> hi/lo bf16 planes ----------
__global__ __launch_bounds__(TPB) void split_w(const float* __restrict__ W,
                                               unsigned short* __restrict__ hi,
                                               unsigned short* __restrict__ lo) {
  const int idx = blockIdx.x * TPB + threadIdx.x;
  const float w = W[idx];
  const unsigned short h = bf16_rne(w);
  hi[idx] = h;
  lo[idx] = bf16_rne(w - bf16_f(h));
}

// ---------- A-fragment plane (packed u32 h via LLC relaxed atomics) ----------
struct APlane { unsigned long long raw[32]; };

__device__ __forceinline__ void load_aplane(APlane& A, const uint32_t* __restrict__ hp,
                                            int row, int lg) {
  const uint32_t* ap = hp + (size_t)row * NH;
#pragma unroll
  for (int kt = 0; kt < 8; ++kt) {
    const int ko = kt * 32 + lg * 8;
#pragma unroll
    for (int e = 0; e < 4; ++e)
      A.raw[kt * 4 + e] = __hip_atomic_load(
          (const unsigned long long*)(ap + ko) + e,
          __ATOMIC_RELAXED, __HIP_MEMORY_SCOPE_AGENT);
  }
}

// acc[g] += A(64x256 rows b0..) @ W(gate rows at h0off)^T, 3-term hi/lo split.
// Fragment mapping proven in rounds 4-6 (absmax 2.44e-4).
__device__ __forceinline__ void gemm_frag(f32x4 acc[4], const APlane& A,
                                          const unsigned short* __restrict__ whi,
                                          const unsigned short* __restrict__ wlo,
                                          int h0off, int lg, int ln16) {
  const unsigned short* bh0 = whi + (size_t)(h0off + ln16) * NH;
  const unsigned short* bl0 = wlo + (size_t)(h0off + ln16) * NH;
#pragma unroll
  for (int kt = 0; kt < 8; ++kt) {
    uint32_t p[8];
#pragma unroll
    for (int e = 0; e < 4; ++e) {
      p[2 * e]     = (uint32_t)A.raw[kt * 4 + e];
      p[2 * e + 1] = (uint32_t)(A.raw[kt * 4 + e] >> 32);
    }
    bf16x8 Ah, Al;
#pragma unroll
    for (int e = 0; e < 8; ++e) {
      Ah[e] = (short)(p[e] >> 16);
      Al[e] = (short)(p[e] & 0xFFFFu);
    }
    const int ko = kt * 32 + lg * 8;
#pragma unroll
    for (int g = 0; g < 4; ++g) {
      const bf16x8 Bh = *(const bf16x8*)(bh0 + (size_t)g * (NH * NH) + ko);
      const bf16x8 Bl = *(const bf16x8*)(bl0 + (size_t)g * (NH * NH) + ko);
      acc[g] = __builtin_amdgcn_mfma_f32_16x16x32_bf16(Ah, Bh, acc[g], 0, 0, 0);
      acc[g] = __builtin_amdgcn_mfma_f32_16x16x32_bf16(Ah, Bl, acc[g], 0, 0, 0);
      acc[g] = __builtin_amdgcn_mfma_f32_16x16x32_bf16(Al, Bh, acc[g], 0, 0, 0);
    }
  }
}

// ---------- split-phase group barrier: per-group monotonic counter ----------
__device__ __forceinline__ void barrier_arrive(unsigned* ctr_line, unsigned* bno, int tx) {
  __syncthreads();  // drains every wave's vmcnt -> all h stores LLC-acked
  if (tx == 0)
    __hip_atomic_fetch_add(ctr_line, 1u, __ATOMIC_RELAXED, __HIP_MEMORY_SCOPE_AGENT);
  ++(*bno);
}
__device__ __forceinline__ void barrier_wait(unsigned* ctr_line, unsigned bno, int tx) {
  if (tx == 0) {
    while (__hip_atomic_load(ctr_line, __ATOMIC_RELAXED, __HIP_MEMORY_SCOPE_AGENT) <
           16u * bno)
      __builtin_amdgcn_s_sleep(2);
  }
  __syncthreads();
  asm volatile("" ::: "memory");
}

// ---------- the whole network in one launch ----------
__global__ __launch_bounds__(TPB, 1) void lstm_persist(
    const float* __restrict__ x,
    const float* __restrict__ eWih0, const float* __restrict__ eb0,
    const float* __restrict__ eb1,
    const float* __restrict__ dWih0, const float* __restrict__ db0,
    const float* __restrict__ db1,
    const float* __restrict__ fcW, const float* __restrict__ fcb,
    const unsigned short* __restrict__ wp,  // 12 planes
    uint32_t* __restrict__ hbase,           // 4 packed h planes
    unsigned* __restrict__ ctr,             // 16 groups x 32 u32 (1 line each)
    float* __restrict__ pred,               // [NHOR][NB]
    float* __restrict__ out) {
  const int tx = threadIdx.x, bx = blockIdx.x;
  const int bt = bx & 15, ht = bx >> 4;   // group bt: blocks == bt (mod 16) -> XCD-uniform under round-robin
  const int b0 = bt * 64, h0off = ht * 16;
  const int wv = tx >> 6, l = tx & 63, lg = l >> 4, ln16 = l & 15;
  const int hcol = h0off + ln16;
  const int arow = b0 + wv * 16 + ln16;      // A-fragment row
  unsigned* ctr_line = &ctr[bt * 32];

  const unsigned short* W_eWhh0_hi = wp + 0 * 2 * PLANE;
  const unsigned short* W_eWhh0_lo = W_eWhh0_hi + PLANE;
  const unsigned short* W_eWih1_hi = wp + 1 * 2 * PLANE;
  const unsigned short* W_eWih1_lo = W_eWih1_hi + PLANE;
  const unsigned short* W_eWhh1_hi = wp + 2 * 2 * PLANE;
  const unsigned short* W_eWhh1_lo = W_eWhh1_hi + PLANE;
  const unsigned short* W_dWhh0_hi = wp + 3 * 2 * PLANE;
  const unsigned short* W_dWhh0_lo = W_dWhh0_hi + PLANE;
  const unsigned short* W_dWih1_hi = wp + 4 * 2 * PLANE;
  const unsigned short* W_dWih1_lo = W_dWih1_hi + PLANE;
  const unsigned short* W_dWhh1_hi = wp + 5 * 2 * PLANE;
  const unsigned short* W_dWhh1_lo = W_dWhh1_hi + PLANE;

  const int HP = NB * NH;
  uint32_t* h0c = hbase + 0 * HP; uint32_t* h0n = hbase + 1 * HP;
  uint32_t* h1c = hbase + 2 * HP; uint32_t* h1n = hbase + 3 * HP;

  // per-thread constants
  float ewv[4], eb0v[4], eb1v[4], dwv[4], db0v[4], db1v[4];
#pragma unroll
  for (int g = 0; g < 4; ++g) {
    ewv[g]  = eWih0[g * NH + hcol];
    eb0v[g] = eb0[g * NH + hcol];
    eb1v[g] = eb1[g * NH + hcol];
    dwv[g]  = dWih0[g * NH + hcol];
    db0v[g] = db0[g * NH + hcol];
    db1v[g] = db1[g * NH + hcol];
  }
  const float fcwv = fcW[hcol];
  const float fcbv = fcb[0];

  float c0r[4] = {0.f, 0.f, 0.f, 0.f};
  float c1r[4] = {0.f, 0.f, 0.f, 0.f};
  unsigned bno = 0;

  // ---- interval s=0: layer0(0) only (no gemm) ----
  {
#pragma unroll
    for (int r = 0; r < 4; ++r) {
      const int b = b0 + wv * 16 + lg * 4 + r;
      const float pv = x[b * NLOOK + 0];
      const float ig = sigm(pv * ewv[0] + eb0v[0]);
      const float fg = sigm(pv * ewv[1] + eb0v[1]);
      const float gg = tanh_(pv * ewv[2] + eb0v[2]);
      const float og = sigm(pv * ewv[3] + eb0v[3]);
      c0r[r] = fg * c0r[r] + ig * gg;
      __hip_atomic_store(&h0n[b * NH + hcol], pack_h(og * tanh_(c0r[r])),
                         __ATOMIC_RELAXED, __HIP_MEMORY_SCOPE_AGENT);
    }
    barrier_arrive(ctr_line, &bno, tx);
    { uint32_t* s0 = h0c; h0c = h0n; h0n = s0; }
  }

  // ---- fused encoder intervals s=1..336: layer1(s-1) + layer0(s) ----
  for (int s = 1; s <= NLOOK; ++s) {
    // prefetch (pre-wait): h1(s-2) plane, x column s
    APlane A1;
    if (s >= 2) load_aplane(A1, h1c, arow, lg);
    float xv[4];
    if (s <= NLOOK - 1) {
#pragma unroll
      for (int r = 0; r < 4; ++r)
        xv[r] = x[(b0 + wv * 16 + lg * 4 + r) * NLOOK + s];
    }
    barrier_wait(ctr_line, bno, tx);   // publishes h0(s-1), h1(s-2)

    APlane A0;
    load_aplane(A0, h0c, arow, lg);    // h0(s-1), shared by both layers' gemms

    // layer1(s-1)
    f32x4 acc1[4] = {};
    gemm_frag(acc1, A0, W_eWih1_hi, W_eWih1_lo, h0off, lg, ln16);
    if (s >= 2) gemm_frag(acc1, A1, W_eWhh1_hi, W_eWhh1_lo, h0off, lg, ln16);
#pragma unroll
    for (int r = 0; r < 4; ++r) {
      const int b = b0 + wv * 16 + lg * 4 + r;
      const float ig = sigm(acc1[0][r] + eb1v[0]);
      const float fg = sigm(acc1[1][r] + eb1v[1]);
      const float gg = tanh_(acc1[2][r] + eb1v[2]);
      const float og = sigm(acc1[3][r] + eb1v[3]);
      c1r[r] = fg * c1r[r] + ig * gg;
      __hip_atomic_store(&h1n[b * NH + hcol], pack_h(og * tanh_(c1r[r])),
                         __ATOMIC_RELAXED, __HIP_MEMORY_SCOPE_AGENT);
    }

    // layer0(s)
    if (s <= NLOOK - 1) {
      f32x4 acc0[4] = {};
      gemm_frag(acc0, A0, W_eWhh0_hi, W_eWhh0_lo, h0off, lg, ln16);
#pragma unroll
      for (int r = 0; r < 4; ++r) {
        const int b = b0 + wv * 16 + lg * 4 + r;
        const float ig = sigm(acc0[0][r] + xv[r] * ewv[0] + eb0v[0]);
        const float fg = sigm(acc0[1][r] + xv[r] * ewv[1] + eb0v[1]);
        const float gg = tanh_(acc0[2][r] + xv[r] * ewv[2] + eb0v[2]);
        const float og = sigm(acc0[3][r] + xv[r] * ewv[3] + eb0v[3]);
        c0r[r] = fg * c0r[r] + ig * gg;
        __hip_atomic_store(&h0n[b * NH + hcol], pack_h(og * tanh_(c0r[r])),
                           __ATOMIC_RELAXED, __HIP_MEMORY_SCOPE_AGENT);
      }
    }
    barrier_arrive(ctr_line, &bno, tx);
    if (s <= NLOOK - 1) { uint32_t* s0 = h0c; h0c = h0n; h0n = s0; }
    { uint32_t* s0 = h1c; h1c = h1n; h1n = s0; }
  }

  // ---- decoder: 2 intervals per step ----
  for (int t = 0; t < NHOR; ++t) {
    // ---- d0: layer0(t) ----
    {
      APlane A0;
      load_aplane(A0, h0c, arow, lg);       // h0(t-1): 2 barriers old -> pre-wait
      float pvx[4];
      if (t == 0) {
#pragma unroll
        for (int r = 0; r < 4; ++r)
          pvx[r] = x[(b0 + wv * 16 + lg * 4 + r) * NLOOK + (NLOOK - 1)];
      }
      barrier_wait(ctr_line, bno, tx);      // publishes pred[t-1]

      float pv[4];
#pragma unroll
      for (int r = 0; r < 4; ++r) {
        const int b = b0 + wv * 16 + lg * 4 + r;
        pv[r] = (t == 0) ? pvx[r]
                         : __hip_atomic_load(&pred[(t - 1) * NB + b],
                                             __ATOMIC_RELAXED, __HIP_MEMORY_SCOPE_AGENT);
      }
      f32x4 acc0[4] = {};
      gemm_frag(acc0, A0, W_dWhh0_hi, W_dWhh0_lo, h0off, lg, ln16);
#pragma unroll
      for (int r = 0; r < 4; ++r) {
        const int b = b0 + wv * 16 + lg * 4 + r;
        const float ig = sigm(acc0[0][r] + pv[r] * dwv[0] + db0v[0]);
        const float fg = sigm(acc0[1][r] + pv[r] * dwv[1] + db0v[1]);
        const float gg = tanh_(acc0[2][r] + pv[r] * dwv[2] + db0v[2]);
        const float og = sigm(acc0[3][r] + pv[r] * dwv[3] + db0v[3]);
        c0r[r] = fg * c0r[r] + ig * gg;
        __hip_atomic_store(&h0n[b * NH + hcol], pack_h(og * tanh_(c0r[r])),
                           __ATOMIC_RELAXED, __HIP_MEMORY_SCOPE_AGENT);
      }
      if (ht == 0 && t >= 1 && ln16 == 0) {
#pragma unroll
        for (int r = 0; r < 4; ++r) {
          const int b = b0 + wv * 16 + lg * 4 + r;
          out[b * NHOR + (t - 1)] = pv[r];
        }
      }
      barrier_arrive(ctr_line, &bno, tx);
      { uint32_t* s0 = h0c; h0c = h0n; h0n = s0; }
    }

    // ---- d1: layer1(t) + fc ----
    {
      APlane A1;
      load_aplane(A1, h1c, arow, lg);       // h1(t-1): 2 barriers old -> pre-wait
      barrier_wait(ctr_line, bno, tx);      // publishes h0(t)

      APlane A0;
      load_aplane(A0, h0c, arow, lg);       // h0(t)
      f32x4 acc1[4] = {};
      gemm_frag(acc1, A0, W_dWih1_hi, W_dWih1_lo, h0off, lg, ln16);
      gemm_frag(acc1, A1, W_dWhh1_hi, W_dWhh1_lo, h0off, lg, ln16);
      float hvr[4];
#pragma unroll
      for (int r = 0; r < 4; ++r) {
        const int b = b0 + wv * 16 + lg * 4 + r;
        const float ig = sigm(acc1[0][r] + db1v[0]);
        const float fg = sigm(acc1[1][r] + db1v[1]);
        const float gg = tanh_(acc1[2][r] + db1v[2]);
        const float og = sigm(acc1[3][r] + db1v[3]);
        c1r[r] = fg * c1r[r] + ig * gg;
        hvr[r] = og * tanh_(c1r[r]);
        __hip_atomic_store(&h1n[b * NH + hcol], pack_h(hvr[r]),
                           __ATOMIC_RELAXED, __HIP_MEMORY_SCOPE_AGENT);
      }
      float s4[4];
#pragma unroll
      for (int r = 0; r < 4; ++r) s4[r] = hvr[r] * fcwv;
#pragma unroll
      for (int m = 1; m < 16; m <<= 1) {
#pragma unroll
        for (int r = 0; r < 4; ++r) s4[r] += __shfl_xor(s4[r], m, 64);
      }
      if (ln16 == 0) {
#pragma unroll
        for (int r = 0; r < 4; ++r) {
          const int b = b0 + wv * 16 + lg * 4 + r;
          float v = s4[r];
          if (ht == 0) v += fcbv;
          atomicAdd(&pred[t * NB + b], v);
        }
      }
      barrier_arrive(ctr_line, &bno, tx);
      { uint32_t* s0 = h1c; h1c = h1n; h1n = s0; }
    }
  }

  // ---- tail: publish final column ----
  barrier_wait(ctr_line, bno, tx);          // publishes pred[167]
  if (ht == 0 && ln16 == 0) {
#pragma unroll
    for (int r = 0; r < 4; ++r) {
      const int b = b0 + wv * 16 + lg * 4 + r;
      out[b * NHOR + (NHOR - 1)] =
          __hip_atomic_load(&pred[(NHOR - 1) * NB + b],
                            __ATOMIC_RELAXED, __HIP_MEMORY_SCOPE_AGENT);
    }
  }
}

extern "C" void kernel_launch(void* const* d_in, const int* in_sizes, int n_in,
                              void* d_out, int out_size, void* d_ws, size_t ws_size,
                              hipStream_t stream) {
  (void)in_sizes; (void)n_in; (void)out_size; (void)ws_size;
  const float* x     = (const float*)d_in[0];
  const float* eWih0 = (const float*)d_in[1];
  const float* eWhh0 = (const float*)d_in[2];
  const float* eb0   = (const float*)d_in[3];
  const float* eWih1 = (const float*)d_in[4];
  const float* eWhh1 = (const float*)d_in[5];
  const float* eb1   = (const float*)d_in[6];
  const float* dWih0 = (const float*)d_in[7];
  const float* dWhh0 = (const float*)d_in[8];
  const float* db0   = (const float*)d_in[9];
  const float* dWih1 = (const float*)d_in[10];
  const float* dWhh1 = (const float*)d_in[11];
  const float* db1   = (const float*)d_in[12];
  const float* fcW   = (const float*)d_in[13];
  const float* fcb   = (const float*)d_in[14];
  float* out = (float*)d_out;

  uint8_t* wsb = (uint8_t*)d_ws;
  unsigned* ctr = (unsigned*)wsb;                              // 16 groups x 128B
  float* pred = (float*)(wsb + 16384);                         // NHOR*NB*4
  unsigned short* wp = (unsigned short*)(wsb + 1048576);       // 12 planes = 6 MiB
  uint32_t* hbase = (uint32_t*)(wsb + 1048576 + (size_t)12 * PLANE * 2);  // 4 MiB

  hipMemsetAsync(d_ws, 0, 16384 + (size_t)NHOR * NB * 4, stream);

  const float* Wsrc[6] = { eWhh0, eWih1, eWhh1, dWhh0, dWih1, dWhh1 };
  for (int m = 0; m < 6; ++m)
    split_w<<<dim3(PLANE / TPB), dim3(TPB), 0, stream>>>(
        Wsrc[m], wp + (size_t)m * 2 * PLANE, wp + (size_t)m * 2 * PLANE + PLANE);

  lstm_persist<<<dim3(256), dim3(TPB), 0, stream>>>(
      x, eWih0, eb0, eb1, dWih0, db0, db1, fcW, fcb,
      wp, hbase, ctr, pred, out);
}

// Round 8
// 14631.685 us; speedup vs baseline: 4.0198x; 1.1263x over previous
//
#include <hip/hip_runtime.h>
#include <stdint.h>
#include <math.h>

#define NB 1024      // batch
#define NH 256       // hidden
#define NG 1024      // 4*NH gate rows
#define NLOOK 336    // encoder steps
#define NHOR 168     // decoder steps
#define TPB 256
#define PLANE (NG * NH)   // 262144 elems per bf16 weight plane

// ---------- bf16 helpers (RNE) ----------
__device__ __forceinline__ unsigned short bf16_rne(float f) {
  union { float f; uint32_t u; } v; v.f = f;
  uint32_t u = v.u;
  u += 0x7FFFu + ((u >> 16) & 1u);
  return (unsigned short)(u >> 16);
}
__device__ __forceinline__ float bf16_f(unsigned short h) {
  union { uint32_t u; float f; } v; v.u = ((uint32_t)h) << 16;
  return v.f;
}
// fast sigmoid/tanh on hw trans pipes (~1e-7 rel err; bf16 split err dominates)
__device__ __forceinline__ float sigm(float x) {
  return __builtin_amdgcn_rcpf(1.0f + __expf(-x));
}
__device__ __forceinline__ float tanh_(float x) {
  return 1.0f - 2.0f * __builtin_amdgcn_rcpf(1.0f + __expf(2.0f * x));
}
// pack h as (hi<<16)|lo where hi=bf16(h), lo=bf16(h - hi)
__device__ __forceinline__ uint32_t pack_h(float hv) {
  const unsigned short hb = bf16_rne(hv);
  const unsigned short lb = bf16_rne(hv - bf16_f(hb));
  return ((uint32_t)hb << 16) | (uint32_t)lb;
}

typedef short bf16x8 __attribute__((ext_vector_type(8)));
typedef float f32x4 __attribute__((ext_vector_type(4)));
typedef uint32_t u32v4 __attribute__((ext_vector_type(4)));

// ---------- weight split prologue: W(fp32) -> hi/lo bf16 planes ----------
__global__ __launch_bounds__(TPB) void split_w(const float* __restrict__ W,
                                               unsigned short* __restrict__ hi,
                                               unsigned short* __restrict__ lo) {
  const int idx = blockIdx.x * TPB + threadIdx.x;
  const float w = W[idx];
  const unsigned short h = bf16_rne(w);
  hi[idx] = h;
  lo[idx] = bf16_rne(w - bf16_f(h));
}

// ---------- wide device-coherent (cross-XCD fresh) loads/stores ----------
// sc0 sc1: bypass stale L1/L2 copies, served at the LLC coherence point,
// but full 16B vector width with normal coalescing (vs 8B atomic slots).
__device__ __forceinline__ void wait_vm0() {
  asm volatile("s_waitcnt vmcnt(0)" ::: "memory");
  __builtin_amdgcn_sched_barrier(0);   // rule #18: no use may hoist above this
}

// ---------- A-fragment plane (16 x 16B coherent loads, issue-only) ----------
struct APlane { u32v4 q[16]; };

__device__ __forceinline__ void aplane_issue(APlane& A, const uint32_t* __restrict__ hp,
                                             int row, int lg) {
  const uint32_t* ap = hp + (size_t)row * NH;
#pragma unroll
  for (int kt = 0; kt < 8; ++kt) {
    const uint32_t* p0 = ap + kt * 32 + lg * 8;
    asm volatile("global_load_dwordx4 %0, %1, off sc0 sc1"
                 : "=v"(A.q[2 * kt]) : "v"(p0));
    asm volatile("global_load_dwordx4 %0, %1, off sc0 sc1"
                 : "=v"(A.q[2 * kt + 1]) : "v"(p0 + 4));
  }
}

// acc[g] += A(16 rows) @ W(gate rows at h0off)^T, 3-term hi/lo split.
// Fragment mapping proven in rounds 4-7 (absmax <= 2.44e-4).
__device__ __forceinline__ void gemm_frag(f32x4 acc[4], const APlane& A,
                                          const unsigned short* __restrict__ whi,
                                          const unsigned short* __restrict__ wlo,
                                          int h0off, int lg, int ln16) {
  const unsigned short* bh0 = whi + (size_t)(h0off + ln16) * NH;
  const unsigned short* bl0 = wlo + (size_t)(h0off + ln16) * NH;
#pragma unroll
  for (int kt = 0; kt < 8; ++kt) {
    bf16x8 Ah, Al;
#pragma unroll
    for (int half = 0; half < 2; ++half)
#pragma unroll
      for (int j = 0; j < 4; ++j) {
        const uint32_t w = A.q[2 * kt + half][j];
        Ah[half * 4 + j] = (short)(w >> 16);
        Al[half * 4 + j] = (short)(w & 0xFFFFu);
      }
    const int ko = kt * 32 + lg * 8;
#pragma unroll
    for (int g = 0; g < 4; ++g) {
      const bf16x8 Bh = *(const bf16x8*)(bh0 + (size_t)g * (NH * NH) + ko);
      const bf16x8 Bl = *(const bf16x8*)(bl0 + (size_t)g * (NH * NH) + ko);
      acc[g] = __builtin_amdgcn_mfma_f32_16x16x32_bf16(Ah, Bh, acc[g], 0, 0, 0);
      acc[g] = __builtin_amdgcn_mfma_f32_16x16x32_bf16(Ah, Bl, acc[g], 0, 0, 0);
      acc[g] = __builtin_amdgcn_mfma_f32_16x16x32_bf16(Al, Bh, acc[g], 0, 0, 0);
    }
  }
}

// ---------- coalesced h-tile store: LDS 64x16 transpose -> 16B coherent stores ----------
__device__ __forceinline__ void store_htile(uint32_t* __restrict__ hplane,
                                            const uint32_t pk[4],
                                            uint32_t (*tr)[65],
                                            int b0, int h0off, int tx,
                                            int wv, int lg, int ln16) {
  __syncthreads();   // previous tr consumers done
#pragma unroll
  for (int r = 0; r < 4; ++r) tr[ln16][wv * 16 + lg * 4 + r] = pk[r];
  __syncthreads();
  const int ri = tx >> 2, c0 = (tx & 3) * 4;
  u32v4 v;
  v[0] = tr[c0 + 0][ri]; v[1] = tr[c0 + 1][ri];
  v[2] = tr[c0 + 2][ri]; v[3] = tr[c0 + 3][ri];
  uint32_t* dst = hplane + (size_t)(b0 + ri) * NH + h0off + c0;
  asm volatile("global_store_dwordx4 %0, %1, off sc0 sc1" :: "v"(dst), "v"(v) : "memory");
}

// ---------- split-phase group barrier: per-group monotonic counter ----------
__device__ __forceinline__ void barrier_arrive(unsigned* ctr_line, unsigned* bno, int tx) {
  asm volatile("s_waitcnt vmcnt(0)" ::: "memory");  // sc stores LLC-acked
  __syncthreads();
  if (tx == 0)
    __hip_atomic_fetch_add(ctr_line, 1u, __ATOMIC_RELAXED, __HIP_MEMORY_SCOPE_AGENT);
  ++(*bno);
}
__device__ __forceinline__ void barrier_wait(unsigned* ctr_line, unsigned bno, int tx) {
  if (tx == 0) {
    while (__hip_atomic_load(ctr_line, __ATOMIC_RELAXED, __HIP_MEMORY_SCOPE_AGENT) <
           16u * bno)
      __builtin_amdgcn_s_sleep(2);
  }
  __syncthreads();
  asm volatile("" ::: "memory");
}

// ---------- the whole network in one launch ----------
__global__ __launch_bounds__(TPB, 1) void lstm_persist(
    const float* __restrict__ x,
    const float* __restrict__ eWih0, const float* __restrict__ eb0,
    const float* __restrict__ eb1,
    const float* __restrict__ dWih0, const float* __restrict__ db0,
    const float* __restrict__ db1,
    const float* __restrict__ fcW, const float* __restrict__ fcb,
    const unsigned short* __restrict__ wp,  // 12 planes
    uint32_t* __restrict__ hbase,           // 4 packed h planes
    unsigned* __restrict__ ctr,             // 16 groups x 32 u32 (1 line each)
    float* __restrict__ pred,               // [NHOR][NB]
    float* __restrict__ out) {
  __shared__ uint32_t tr[16][65];           // 4.2 KB transpose staging
  const int tx = threadIdx.x, bx = blockIdx.x;
  const int bt = bx & 15, ht = bx >> 4;
  const int b0 = bt * 64, h0off = ht * 16;
  const int wv = tx >> 6, l = tx & 63, lg = l >> 4, ln16 = l & 15;
  const int hcol = h0off + ln16;
  const int arow = b0 + wv * 16 + ln16;      // A-fragment row
  unsigned* ctr_line = &ctr[bt * 32];

  const unsigned short* W_eWhh0_hi = wp + 0 * 2 * PLANE;
  const unsigned short* W_eWhh0_lo = W_eWhh0_hi + PLANE;
  const unsigned short* W_eWih1_hi = wp + 1 * 2 * PLANE;
  const unsigned short* W_eWih1_lo = W_eWih1_hi + PLANE;
  const unsigned short* W_eWhh1_hi = wp + 2 * 2 * PLANE;
  const unsigned short* W_eWhh1_lo = W_eWhh1_hi + PLANE;
  const unsigned short* W_dWhh0_hi = wp + 3 * 2 * PLANE;
  const unsigned short* W_dWhh0_lo = W_dWhh0_hi + PLANE;
  const unsigned short* W_dWih1_hi = wp + 4 * 2 * PLANE;
  const unsigned short* W_dWih1_lo = W_dWih1_hi + PLANE;
  const unsigned short* W_dWhh1_hi = wp + 5 * 2 * PLANE;
  const unsigned short* W_dWhh1_lo = W_dWhh1_hi + PLANE;

  const int HP = NB * NH;
  uint32_t* h0c = hbase + 0 * HP; uint32_t* h0n = hbase + 1 * HP;
  uint32_t* h1c = hbase + 2 * HP; uint32_t* h1n = hbase + 3 * HP;

  // per-thread constants
  float ewv[4], eb0v[4], eb1v[4], dwv[4], db0v[4], db1v[4];
#pragma unroll
  for (int g = 0; g < 4; ++g) {
    ewv[g]  = eWih0[g * NH + hcol];
    eb0v[g] = eb0[g * NH + hcol];
    eb1v[g] = eb1[g * NH + hcol];
    dwv[g]  = dWih0[g * NH + hcol];
    db0v[g] = db0[g * NH + hcol];
    db1v[g] = db1[g * NH + hcol];
  }
  const float fcwv = fcW[hcol];
  const float fcbv = fcb[0];

  float c0r[4] = {0.f, 0.f, 0.f, 0.f};
  float c1r[4] = {0.f, 0.f, 0.f, 0.f};
  unsigned bno = 0;

  // ---- interval s=0: layer0(0) only (no gemm) ----
  {
    uint32_t pk[4];
#pragma unroll
    for (int r = 0; r < 4; ++r) {
      const int b = b0 + wv * 16 + lg * 4 + r;
      const float pv = x[b * NLOOK + 0];
      const float ig = sigm(pv * ewv[0] + eb0v[0]);
      const float fg = sigm(pv * ewv[1] + eb0v[1]);
      const float gg = tanh_(pv * ewv[2] + eb0v[2]);
      const float og = sigm(pv * ewv[3] + eb0v[3]);
      c0r[r] = fg * c0r[r] + ig * gg;
      pk[r] = pack_h(og * tanh_(c0r[r]));
    }
    store_htile(h0n, pk, tr, b0, h0off, tx, wv, lg, ln16);
    barrier_arrive(ctr_line, &bno, tx);
    { uint32_t* s0 = h0c; h0c = h0n; h0n = s0; }
  }

  // ---- fused encoder intervals s=1..336: layer1(s-1) + layer0(s) ----
  for (int s = 1; s <= NLOOK; ++s) {
    // prefetch (pre-wait): h1(s-2) plane (2 barriers old), x column s
    APlane A1;
    if (s >= 2) aplane_issue(A1, h1c, arow, lg);
    float xv[4];
    if (s <= NLOOK - 1) {
#pragma unroll
      for (int r = 0; r < 4; ++r)
        xv[r] = x[(b0 + wv * 16 + lg * 4 + r) * NLOOK + s];
    }
    barrier_wait(ctr_line, bno, tx);   // publishes h0(s-1), h1(s-2)

    APlane A0;
    aplane_issue(A0, h0c, arow, lg);   // h0(s-1), shared by both layers' gemms
    wait_vm0();

    // layer1(s-1)
    f32x4 acc1[4] = {};
    gemm_frag(acc1, A0, W_eWih1_hi, W_eWih1_lo, h0off, lg, ln16);
    if (s >= 2) gemm_frag(acc1, A1, W_eWhh1_hi, W_eWhh1_lo, h0off, lg, ln16);
    uint32_t pk1[4];
#pragma unroll
    for (int r = 0; r < 4; ++r) {
      const float ig = sigm(acc1[0][r] + eb1v[0]);
      const float fg = sigm(acc1[1][r] + eb1v[1]);
      const float gg = tanh_(acc1[2][r] + eb1v[2]);
      const float og = sigm(acc1[3][r] + eb1v[3]);
      c1r[r] = fg * c1r[r] + ig * gg;
      pk1[r] = pack_h(og * tanh_(c1r[r]));
    }
    store_htile(h1n, pk1, tr, b0, h0off, tx, wv, lg, ln16);

    // layer0(s)
    if (s <= NLOOK - 1) {
      f32x4 acc0[4] = {};
      gemm_frag(acc0, A0, W_eWhh0_hi, W_eWhh0_lo, h0off, lg, ln16);
      uint32_t pk0[4];
#pragma unroll
      for (int r = 0; r < 4; ++r) {
        const float ig = sigm(acc0[0][r] + xv[r] * ewv[0] + eb0v[0]);
        const float fg = sigm(acc0[1][r] + xv[r] * ewv[1] + eb0v[1]);
        const float gg = tanh_(acc0[2][r] + xv[r] * ewv[2] + eb0v[2]);
        const float og = sigm(acc0[3][r] + xv[r] * ewv[3] + eb0v[3]);
        c0r[r] = fg * c0r[r] + ig * gg;
        pk0[r] = pack_h(og * tanh_(c0r[r]));
      }
      store_htile(h0n, pk0, tr, b0, h0off, tx, wv, lg, ln16);
    }
    barrier_arrive(ctr_line, &bno, tx);
    if (s <= NLOOK - 1) { uint32_t* s0 = h0c; h0c = h0n; h0n = s0; }
    { uint32_t* s0 = h1c; h1c = h1n; h1n = s0; }
  }

  // ---- decoder: 2 intervals per step ----
  for (int t = 0; t < NHOR; ++t) {
    // ---- d0: layer0(t) ----
    {
      APlane A0;
      aplane_issue(A0, h0c, arow, lg);      // h0(t-1): 2 barriers old -> pre-wait
      float pvx[4];
      if (t == 0) {
#pragma unroll
        for (int r = 0; r < 4; ++r)
          pvx[r] = x[(b0 + wv * 16 + lg * 4 + r) * NLOOK + (NLOOK - 1)];
      }
      barrier_wait(ctr_line, bno, tx);      // publishes pred[t-1]
      wait_vm0();

      float pv[4];
#pragma unroll
      for (int r = 0; r < 4; ++r) {
        const int b = b0 + wv * 16 + lg * 4 + r;
        pv[r] = (t == 0) ? pvx[r]
                         : __hip_atomic_load(&pred[(t - 1) * NB + b],
                                             __ATOMIC_RELAXED, __HIP_MEMORY_SCOPE_AGENT);
      }
      f32x4 acc0[4] = {};
      gemm_frag(acc0, A0, W_dWhh0_hi, W_dWhh0_lo, h0off, lg, ln16);
      uint32_t pk0[4];
#pragma unroll
      for (int r = 0; r < 4; ++r) {
        const float ig = sigm(acc0[0][r] + pv[r] * dwv[0] + db0v[0]);
        const float fg = sigm(acc0[1][r] + pv[r] * dwv[1] + db0v[1]);
        const float gg = tanh_(acc0[2][r] + pv[r] * dwv[2] + db0v[2]);
        const float og = sigm(acc0[3][r] + pv[r] * dwv[3] + db0v[3]);
        c0r[r] = fg * c0r[r] + ig * gg;
        pk0[r] = pack_h(og * tanh_(c0r[r]));
      }
      store_htile(h0n, pk0, tr, b0, h0off, tx, wv, lg, ln16);
      if (ht == 0 && t >= 1 && ln16 == 0) {
#pragma unroll
        for (int r = 0; r < 4; ++r) {
          const int b = b0 + wv * 16 + lg * 4 + r;
          out[b * NHOR + (t - 1)] = pv[r];
        }
      }
      barrier_arrive(ctr_line, &bno, tx);
      { uint32_t* s0 = h0c; h0c = h0n; h0n = s0; }
    }

    // ---- d1: layer1(t) + fc ----
    {
      APlane A1;
      aplane_issue(A1, h1c, arow, lg);      // h1(t-1): 2 barriers old -> pre-wait
      barrier_wait(ctr_line, bno, tx);      // publishes h0(t)

      APlane A0;
      aplane_issue(A0, h0c, arow, lg);      // h0(t)
      wait_vm0();

      f32x4 acc1[4] = {};
      gemm_frag(acc1, A0, W_dWih1_hi, W_dWih1_lo, h0off, lg, ln16);
      gemm_frag(acc1, A1, W_dWhh1_hi, W_dWhh1_lo, h0off, lg, ln16);
      float hvr[4];
      uint32_t pk1[4];
#pragma unroll
      for (int r = 0; r < 4; ++r) {
        const float ig = sigm(acc1[0][r] + db1v[0]);
        const float fg = sigm(acc1[1][r] + db1v[1]);
        const float gg = tanh_(acc1[2][r] + db1v[2]);
        const float og = sigm(acc1[3][r] + db1v[3]);
        c1r[r] = fg * c1r[r] + ig * gg;
        hvr[r] = og * tanh_(c1r[r]);
        pk1[r] = pack_h(hvr[r]);
      }
      store_htile(h1n, pk1, tr, b0, h0off, tx, wv, lg, ln16);

      float s4[4];
#pragma unroll
      for (int r = 0; r < 4; ++r) s4[r] = hvr[r] * fcwv;
#pragma unroll
      for (int m = 1; m < 16; m <<= 1) {
#pragma unroll
        for (int r = 0; r < 4; ++r) s4[r] += __shfl_xor(s4[r], m, 64);
      }
      if (ln16 == 0) {
#pragma unroll
        for (int r = 0; r < 4; ++r) {
          const int b = b0 + wv * 16 + lg * 4 + r;
          float v = s4[r];
          if (ht == 0) v += fcbv;
          atomicAdd(&pred[t * NB + b], v);
        }
      }
      barrier_arrive(ctr_line, &bno, tx);
      { uint32_t* s0 = h1c; h1c = h1n; h1n = s0; }
    }
  }

  // ---- tail: publish final column ----
  barrier_wait(ctr_line, bno, tx);          // publishes pred[167]
  if (ht == 0 && ln16 == 0) {
#pragma unroll
    for (int r = 0; r < 4; ++r) {
      const int b = b0 + wv * 16 + lg * 4 + r;
      out[b * NHOR + (NHOR - 1)] =
          __hip_atomic_load(&pred[(NHOR - 1) * NB + b],
                            __ATOMIC_RELAXED, __HIP_MEMORY_SCOPE_AGENT);
    }
  }
}

extern "C" void kernel_launch(void* const* d_in, const int* in_sizes, int n_in,
                              void* d_out, int out_size, void* d_ws, size_t ws_size,
                              hipStream_t stream) {
  (void)in_sizes; (void)n_in; (void)out_size; (void)ws_size;
  const float* x     = (const float*)d_in[0];
  const float* eWih0 = (const float*)d_in[1];
  const float* eWhh0 = (const float*)d_in[2];
  const float* eb0   = (const float*)d_in[3];
  const float* eWih1 = (const float*)d_in[4];
  const float* eWhh1 = (const float*)d_in[5];
  const float* eb1   = (const float*)d_in[6];
  const float* dWih0 = (const float*)d_in[7];
  const float* dWhh0 = (const float*)d_in[8];
  const float* db0   = (const float*)d_in[9];
  const float* dWih1 = (const float*)d_in[10];
  const float* dWhh1 = (const float*)d_in[11];
  const float* db1   = (const float*)d_in[12];
  const float* fcW   = (const float*)d_in[13];
  const float* fcb   = (const float*)d_in[14];
  float* out = (float*)d_out;

  uint8_t* wsb = (uint8_t*)d_ws;
  unsigned* ctr = (unsigned*)wsb;                              // 16 groups x 128B
  float* pred = (float*)(wsb + 16384);                         // NHOR*NB*4
  unsigned short* wp = (unsigned short*)(wsb + 1048576);       // 12 planes = 6 MiB
  uint32_t* hbase = (uint32_t*)(wsb + 1048576 + (size_t)12 * PLANE * 2);  // 4 MiB

  hipMemsetAsync(d_ws, 0, 16384 + (size_t)NHOR * NB * 4, stream);

  const float* Wsrc[6] = { eWhh0, eWih1, eWhh1, dWhh0, dWih1, dWhh1 };
  for (int m = 0; m < 6; ++m)
    split_w<<<dim3(PLANE / TPB), dim3(TPB), 0, stream>>>(
        Wsrc[m], wp + (size_t)m * 2 * PLANE, wp + (size_t)m * 2 * PLANE + PLANE);

  lstm_persist<<<dim3(256), dim3(TPB), 0, stream>>>(
      x, eWih0, eb0, eb1, dWih0, db0, db1, fcW, fcb,
      wp, hbase, ctr, pred, out);
}